// Round 1
// baseline (188.116 us; speedup 1.0000x reference)
//
#include <hip/hip_runtime.h>

// EdgeConv with KNN graph: B=8, N=4096, D=3, E=64, K=32.
// === R17: R16 body (86.4 us/dispatch) + two VALU-count cuts ===
// Counter evidence (R16): VALUBusy 70%, HBM 1.5%, MfmaUtil 0, Occ 51%
// -> pure VALU-issue bound, ~2250 VALU instr/point; sweep is only ~400.
// Changes (both bit-exact wrt R16's selection & output):
//  (1) SPECULATIVE FUSED COMPACT-COUNT: compaction's running `base` IS
//      cnt_lt(H). Run compaction directly with the sampled H; if base in
//      [32,64] (common case, E[count]~44) the pool is byte-identical to
//      R16's and the initial cnt_lt pass (~150-200 VALU) is skipped.
//      Fallback: exact R16 gallop/bisect search + recompact.
//  (2) PACKED-PAIR EPILOGUE: stage the 32 selected deltas in per-wave LDS
//      scratch (overlaid on the dead pool region), broadcast-read f32x2
//      pairs (same-address ds_read_b64 = conflict-free) and project with
//      v_pk_fma_f32 / v_pk_max_f32. Same fma chain per element; fmax
//      regrouping is exact. Replaces 96 v_readlane + 128 scalar fma
//      (~450 issue-cyc) with ~64 pk ops + 48 DS ops (~200 issue-cyc).
// Unchanged: sweep math (BIT-IDENTICAL packed fmaf chain, self-dist==0),
//  u16 monotone-truncation keys, per-point sampled threshold, exact-fp32
//  partial bitonic with lower-index tie-break == jax.lax.top_k,
//  2048x16 grid, fresh per-point H, 3 planes + scratch (51 KB -> 3 blk/CU).
// SPILL DISCIPLINE (R2/R3): every loop touching pk[] FULLY unrolled;
// (512,6) 85-VGPR budget. TRIPWIRE: FETCH>6MB.

#define NPTS 4096
#define KNN  32

#define WFENCE() __asm__ volatile("s_waitcnt lgkmcnt(0)" ::: "memory")

typedef unsigned short u16x2 __attribute__((ext_vector_type(2)));
typedef float          f32x2 __attribute__((ext_vector_type(2)));

__device__ __forceinline__ unsigned lane_prefix(unsigned long long m) {
    return __builtin_amdgcn_mbcnt_hi((unsigned)(m >> 32),
           __builtin_amdgcn_mbcnt_lo((unsigned)m, 0u));
}
__device__ __forceinline__ unsigned pk_min_u16(unsigned a, unsigned b) {
    return __builtin_bit_cast(unsigned, __builtin_elementwise_min(
        __builtin_bit_cast(u16x2, a), __builtin_bit_cast(u16x2, b)));
}
// lo16 = top16(d0), hi16 = top16(d1)
__device__ __forceinline__ unsigned pack_keys(float d0, float d1) {
    return __builtin_amdgcn_perm(__builtin_bit_cast(unsigned, d1),
                                 __builtin_bit_cast(unsigned, d0), 0x07060302u);
}

__global__ __launch_bounds__(512, 6)
void edgeconv_knn_kernel(const float* __restrict__ x,
                         const float* __restrict__ theta_w,
                         const float* __restrict__ theta_b,
                         const float* __restrict__ phi_w,
                         const float* __restrict__ phi_b,
                         float* __restrict__ out)
{
    __shared__ float s_x[NPTS];          // 16 KB per plane (48 KB total)
    __shared__ float s_y[NPTS];
    __shared__ float s_z[NPTS];
    // per-wave scratch: first 64 u32 = survivor pool; later reused as
    // 96 floats of neighbor deltas (dx[32] dy[32] dz[32]) for the epilogue.
    __shared__ float s_scratch[8][96];   // 3 KB

    const int tid  = threadIdx.x;
    const int wv   = tid >> 6;
    const int lane = tid & 63;

    const int b  = blockIdx.x >> 8;        // 256 blocks per batch
    const int i0 = (blockIdx.x & 255) << 4;// 16 points per block (2 per wave)

    // lane == output channel e
    const float tw0 = theta_w[lane];
    const float tw1 = theta_w[64 + lane];
    const float tw2 = theta_w[128 + lane];
    const float tbv = theta_b[lane];
    const float pw0 = phi_w[lane];
    const float pw1 = phi_w[64 + lane];
    const float pw2 = phi_w[128 + lane];
    const float pbv = phi_b[lane];

    const f32x2 TW0 = {tw0, tw0}, TW1 = {tw1, tw1}, TW2 = {tw2, tw2};

    const float* xb = x + (size_t)b * NPTS * 3;
    for (int p = tid; p < NPTS; p += 512) {
        s_x[p] = xb[p * 3 + 0];
        s_y[p] = xb[p * 3 + 1];
        s_z[p] = xb[p * 3 + 2];
    }
    __syncthreads();

    unsigned* poolw = (unsigned*)&s_scratch[wv][0];
    float*    wbuf  = &s_scratch[wv][0];

    for (int r = 0; r < 2; ++r) {
        const int i = i0 + wv * 2 + r;
        const float px = s_x[i], py = s_y[i], pz = s_z[i];
        const float sqi = fmaf(pz, pz, fmaf(py, py, px * px));
        const f32x2 PX2 = {px, px}, PY2 = {py, py}, PZ2 = {pz, pz};
        const f32x2 SQI2 = {sqi, sqi};
        const f32x2 N2   = {-2.0f, -2.0f};
        const f32x2 Z02  = {0.0f, 0.0f};

        // ---- sweep: lane owns candidates j = 256*t + 4*lane + {0..3} ----
        // slot s=0..63 -> j = ((s>>2)<<8) + (lane<<2) + (s&3)
        unsigned pk[32];
        unsigned pmin = 0xFFFFFFFFu;
        #pragma unroll
        for (int t = 0; t < 16; ++t) {
            const int jb = (t << 8) + (lane << 2);
            const float4 QX = *(const float4*)&s_x[jb];
            const float4 QY = *(const float4*)&s_y[jb];
            const float4 QZ = *(const float4*)&s_z[jb];
            const f32x2 X0 = {QX.x, QX.y}, X1 = {QX.z, QX.w};
            const f32x2 Y0 = {QY.x, QY.y}, Y1 = {QY.z, QY.w};
            const f32x2 Zc0 = {QZ.x, QZ.y}, Zc1 = {QZ.z, QZ.w};
            // sq_j with the identical chain: fma(z,z, fma(y,y, x*x))
            const f32x2 S0 = __builtin_elementwise_fma(Zc0, Zc0,
                             __builtin_elementwise_fma(Y0, Y0, X0 * X0));
            const f32x2 S1 = __builtin_elementwise_fma(Zc1, Zc1,
                             __builtin_elementwise_fma(Y1, Y1, X1 * X1));
            // dot with the identical chain: fma(pz,qz, fma(py,qy, px*qx))
            const f32x2 dt0 = __builtin_elementwise_fma(PZ2, Zc0,
                              __builtin_elementwise_fma(PY2, Y0, PX2 * X0));
            const f32x2 dt1 = __builtin_elementwise_fma(PZ2, Zc1,
                              __builtin_elementwise_fma(PY2, Y1, PX2 * X1));
            f32x2 d0 = __builtin_elementwise_fma(N2, dt0, SQI2 + S0);
            f32x2 d1 = __builtin_elementwise_fma(N2, dt1, SQI2 + S1);
            d0 = __builtin_elementwise_max(d0, Z02);
            d1 = __builtin_elementwise_max(d1, Z02);
            pk[2 * t]     = pack_keys(d0.x, d0.y);
            pk[2 * t + 1] = pack_keys(d1.x, d1.y);
            pmin = pk_min_u16(pmin, pk[2 * t]);
            pmin = pk_min_u16(pmin, pk[2 * t + 1]);
        }
        unsigned mn = min(pmin & 0xFFFFu, pmin >> 16);   // per-lane min (u16)

        // ---- PER-POINT bitonic sort of 64 lane-minima -> sampled threshold
        #pragma unroll
        for (int k = 2; k <= 64; k <<= 1) {
            #pragma unroll
            for (int jj = k >> 1; jj >= 1; jj >>= 1) {
                const unsigned o = (unsigned)__shfl_xor((int)mn, jj, 64);
                const bool wantmin = (((lane & k) == 0) == ((lane & jj) == 0));
                const bool less = (mn < o);
                if (less != wantmin) mn = o;
            }
        }
        unsigned H = (unsigned)__builtin_amdgcn_readlane((int)mn, 32);

        // wave-uniform count of u16 keys strictly below T (ballot -> scalar)
        auto cnt_lt = [&](unsigned T) -> unsigned {
            unsigned c = 0;
            #pragma unroll
            for (int k2 = 0; k2 < 32; ++k2) {
                c += (unsigned)__popcll(__ballot((pk[k2] & 0xFFFFu) < T));
                c += (unsigned)__popcll(__ballot((pk[k2] >> 16)     < T));
            }
            return c;
        };

        // ---- compaction (also returns the FULL count of keys < T) ----
        auto compact = [&](unsigned T) -> unsigned {
            WFENCE();                        // prior scratch consumers done
            unsigned base = 0;
            #pragma unroll
            for (int s = 0; s < 64; ++s) {
                const unsigned kk = (s & 1) ? (pk[s >> 1] >> 16)
                                            : (pk[s >> 1] & 0xFFFFu);
                const bool pred = kk < T;
                const unsigned long long bm = __ballot(pred);
                if (bm) {
                    if (pred) {
                        const unsigned pos = base + lane_prefix(bm);
                        if (pos < 64u)
                            poolw[pos] =
                                (unsigned)(((s >> 2) << 8) + (lane << 2) + (s & 3));
                    }
                    base += (unsigned)__popcll(bm);
                }
            }
            WFENCE();
            return base;
        };

        // ---- speculative fused compact-count with sampled H ----
        // base == cnt_lt(H) exactly; common case lands in [32,64] and the
        // pool is byte-identical to the count-then-compact path.
        unsigned c = compact(H);
        if (c < KNN || c > 64u) {
            // fallback: exact R16 threshold search, then recompact
            unsigned L = 0u;
            if (c < KNN) {                   // raise by octaves (exp LSB 0x80)
                unsigned step = 0x80u;
                do {
                    unsigned Hn = H + step;
                    if (Hn > 0xFFFFu) Hn = 0xFFFFu;
                    L = H; H = Hn; step <<= 1;
                    c = cnt_lt(H);
                } while (c < KNN);
            }
            while (c > 64u && (H - L) > 1u) {
                const unsigned M  = L + ((H - L) >> 1);
                const unsigned cm = cnt_lt(M);
                if (cm >= KNN) { H = M; c = cm; } else { L = M; }
            }
            c = compact(H);
        }
        const unsigned m = c < 64u ? c : 64u;   // m >= 32 guaranteed

        // ---- exact fp32 keys for pool members (identical op chain) ----
        unsigned myk = 0xFFFFFFFFu;
        unsigned myj = 0u;                   // sentinel, never selected (m>=32)
        if ((unsigned)lane < m) {
            myj = poolw[lane];
            const float qx = s_x[myj], qy = s_y[myj], qz = s_z[myj];
            const float sqj = fmaf(qz, qz, fmaf(qy, qy, qx * qx));
            const float dt  = fmaf(pz, qz, fmaf(py, qy, px * qx));
            float d = fmaf(-2.0f, dt, sqi + sqj);
            d = fmaxf(d, 0.0f);
            myk = __builtin_bit_cast(unsigned, d);
        }

        // ---- partial bitonic: 32-sorts + one merge -> bottom-32 unordered ----
        #pragma unroll
        for (int k = 2; k <= 32; k <<= 1) {
            #pragma unroll
            for (int jj = k >> 1; jj >= 1; jj >>= 1) {
                const unsigned ok = (unsigned)__shfl_xor((int)myk, jj, 64);
                const unsigned oj = (unsigned)__shfl_xor((int)myj, jj, 64);
                const bool wantmin = (((lane & k) == 0) == ((lane & jj) == 0));
                const bool less = (myk < ok) || (myk == ok && myj < oj);
                if (less != wantmin) { myk = ok; myj = oj; }
            }
        }
        {   // k=64, jj=32: lanes 0..31 <- the 32 smallest (unordered)
            const unsigned ok = (unsigned)__shfl_xor((int)myk, 32, 64);
            const unsigned oj = (unsigned)__shfl_xor((int)myj, 32, 64);
            const bool wantmin = ((lane & 32) == 0);
            const bool less = (myk < ok) || (myk == ok && myj < oj);
            if (less != wantmin) { myk = ok; myj = oj; }
        }

        // ---- epilogue: lane = channel e; packed-pair max over 32 selected --
        // Stage deltas in per-wave scratch (pool region is dead now); all
        // lanes broadcast-read f32x2 pairs (conflict-free) and project with
        // v_pk_fma_f32. Same fma chain per element; fmax regroup is exact.
        WFENCE();                            // pool reads done before overwrite
        if (lane < KNN) {
            wbuf[lane]      = s_x[myj] - px;
            wbuf[32 + lane] = s_y[myj] - py;
            wbuf[64 + lane] = s_z[myj] - pz;
        }
        WFENCE();                            // deltas visible to whole wave

        const float basev = tbv + pbv + fmaf(pw2, pz, fmaf(pw1, py, pw0 * px));
        f32x2 mx2 = {-3.0e38f, -3.0e38f};
        #pragma unroll
        for (int t = 0; t < 16; ++t) {
            const f32x2 ndx = *(const f32x2*)&wbuf[2 * t];
            const f32x2 ndy = *(const f32x2*)&wbuf[32 + 2 * t];
            const f32x2 ndz = *(const f32x2*)&wbuf[64 + 2 * t];
            const f32x2 proj = __builtin_elementwise_fma(TW2, ndz,
                               __builtin_elementwise_fma(TW1, ndy, TW0 * ndx));
            mx2 = __builtin_elementwise_max(mx2, proj);
        }
        const float mx = fmaxf(mx2.x, mx2.y);
        out[(((size_t)b * NPTS + (size_t)i) << 6) + lane] = mx + basev;
    }
}

extern "C" void kernel_launch(void* const* d_in, const int* in_sizes, int n_in,
                              void* d_out, int out_size, void* d_ws, size_t ws_size,
                              hipStream_t stream) {
    const float* x  = (const float*)d_in[0];
    const float* tw = (const float*)d_in[1];
    const float* tb = (const float*)d_in[2];
    const float* pw = (const float*)d_in[3];
    const float* pb = (const float*)d_in[4];
    float* out = (float*)d_out;

    dim3 grid(8 * 256);   // 2048 blocks x 16 pts, fresh per-point H
    dim3 block(512);
    hipLaunchKernelGGL(edgeconv_knn_kernel, grid, block, 0, stream,
                       x, tw, tb, pw, pb, out);
}

// Round 2
// 129.997 us; speedup vs baseline: 1.4471x; 1.4471x over previous
//
#include <hip/hip_runtime.h>

// EdgeConv with KNN graph: B=8, N=4096, D=3, E=64, K=32.
// === R18: R16 selection body (86.4 us verified) + packed-pair epilogue ONLY ===
// R17 post-mortem: FETCH 1.7->61.6MB, WRITE 8->237MB, VALUBusy 70->36%
// -> pk[32] spilled to scratch. Cause: `compact` lambda with TWO call sites
// (speculative + fallback) put two unrolled pk-regions under divergent
// control flow; regalloc demoted pk[] to scratch (rule-#20 signature).
// The packed epilogue (straight-line) is exonerated by the counter shape.
// R18 isolates it: selection path restored to R16 EXACTLY (initial cnt_lt,
// gallop/bisect, ONE inlined compaction), epilogue = LDS-staged deltas +
// v_pk_fma_f32 broadcast pairs (bit-exact: same per-element fma chain,
// fmax regroup exact on finite floats; R17 absmax unchanged confirms).
// Expected: FETCH ~1.7MB, WRITE ~8MB (spill tripwire clear), VALUBusy ~70%,
// dispatch ~79-81 us.
// Unchanged from R16: sweep math (BIT-IDENTICAL packed fmaf chain),
//  u16 monotone-truncation keys, per-point sampled threshold, exact-fp32
//  partial bitonic with lower-index tie-break == jax.lax.top_k,
//  2048x16 grid, fresh per-point H, 3 planes (48KB) + 3KB scratch -> 3 blk/CU.
// SPILL DISCIPLINE (R2/R3): every loop touching pk[] FULLY unrolled, ONE
// textual instance of each; (512,6) 85-VGPR budget. TRIPWIRE: FETCH>6MB.

#define NPTS 4096
#define KNN  32

#define WFENCE() __asm__ volatile("s_waitcnt lgkmcnt(0)" ::: "memory")

typedef unsigned short u16x2 __attribute__((ext_vector_type(2)));
typedef float          f32x2 __attribute__((ext_vector_type(2)));

__device__ __forceinline__ unsigned lane_prefix(unsigned long long m) {
    return __builtin_amdgcn_mbcnt_hi((unsigned)(m >> 32),
           __builtin_amdgcn_mbcnt_lo((unsigned)m, 0u));
}
__device__ __forceinline__ unsigned pk_min_u16(unsigned a, unsigned b) {
    return __builtin_bit_cast(unsigned, __builtin_elementwise_min(
        __builtin_bit_cast(u16x2, a), __builtin_bit_cast(u16x2, b)));
}
// lo16 = top16(d0), hi16 = top16(d1)
__device__ __forceinline__ unsigned pack_keys(float d0, float d1) {
    return __builtin_amdgcn_perm(__builtin_bit_cast(unsigned, d1),
                                 __builtin_bit_cast(unsigned, d0), 0x07060302u);
}

__global__ __launch_bounds__(512, 6)
void edgeconv_knn_kernel(const float* __restrict__ x,
                         const float* __restrict__ theta_w,
                         const float* __restrict__ theta_b,
                         const float* __restrict__ phi_w,
                         const float* __restrict__ phi_b,
                         float* __restrict__ out)
{
    __shared__ float s_x[NPTS];          // 16 KB per plane (48 KB total)
    __shared__ float s_y[NPTS];
    __shared__ float s_z[NPTS];
    // per-wave scratch: first 64 u32 = survivor pool (selection phase);
    // then reused as dx[32] dy[32] dz[32] floats for the packed epilogue.
    __shared__ float s_scratch[8][96];   // 3 KB

    const int tid  = threadIdx.x;
    const int wv   = tid >> 6;
    const int lane = tid & 63;

    const int b  = blockIdx.x >> 8;        // 256 blocks per batch
    const int i0 = (blockIdx.x & 255) << 4;// 16 points per block (2 per wave)

    // lane == output channel e
    const float tw0 = theta_w[lane];
    const float tw1 = theta_w[64 + lane];
    const float tw2 = theta_w[128 + lane];
    const float tbv = theta_b[lane];
    const float pw0 = phi_w[lane];
    const float pw1 = phi_w[64 + lane];
    const float pw2 = phi_w[128 + lane];
    const float pbv = phi_b[lane];

    const f32x2 TW0 = {tw0, tw0}, TW1 = {tw1, tw1}, TW2 = {tw2, tw2};

    const float* xb = x + (size_t)b * NPTS * 3;
    for (int p = tid; p < NPTS; p += 512) {
        s_x[p] = xb[p * 3 + 0];
        s_y[p] = xb[p * 3 + 1];
        s_z[p] = xb[p * 3 + 2];
    }
    __syncthreads();

    unsigned* poolw = (unsigned*)&s_scratch[wv][0];
    float*    wbuf  = &s_scratch[wv][0];

    for (int r = 0; r < 2; ++r) {
        const int i = i0 + wv * 2 + r;
        const float px = s_x[i], py = s_y[i], pz = s_z[i];
        const float sqi = fmaf(pz, pz, fmaf(py, py, px * px));
        const f32x2 PX2 = {px, px}, PY2 = {py, py}, PZ2 = {pz, pz};
        const f32x2 SQI2 = {sqi, sqi};
        const f32x2 N2   = {-2.0f, -2.0f};
        const f32x2 Z02  = {0.0f, 0.0f};

        // ---- sweep: lane owns candidates j = 256*t + 4*lane + {0..3} ----
        // slot s=0..63 -> j = ((s>>2)<<8) + (lane<<2) + (s&3)
        unsigned pk[32];
        unsigned pmin = 0xFFFFFFFFu;
        #pragma unroll
        for (int t = 0; t < 16; ++t) {
            const int jb = (t << 8) + (lane << 2);
            const float4 QX = *(const float4*)&s_x[jb];
            const float4 QY = *(const float4*)&s_y[jb];
            const float4 QZ = *(const float4*)&s_z[jb];
            const f32x2 X0 = {QX.x, QX.y}, X1 = {QX.z, QX.w};
            const f32x2 Y0 = {QY.x, QY.y}, Y1 = {QY.z, QY.w};
            const f32x2 Zc0 = {QZ.x, QZ.y}, Zc1 = {QZ.z, QZ.w};
            // sq_j with the identical chain: fma(z,z, fma(y,y, x*x))
            const f32x2 S0 = __builtin_elementwise_fma(Zc0, Zc0,
                             __builtin_elementwise_fma(Y0, Y0, X0 * X0));
            const f32x2 S1 = __builtin_elementwise_fma(Zc1, Zc1,
                             __builtin_elementwise_fma(Y1, Y1, X1 * X1));
            // dot with the identical chain: fma(pz,qz, fma(py,qy, px*qx))
            const f32x2 dt0 = __builtin_elementwise_fma(PZ2, Zc0,
                              __builtin_elementwise_fma(PY2, Y0, PX2 * X0));
            const f32x2 dt1 = __builtin_elementwise_fma(PZ2, Zc1,
                              __builtin_elementwise_fma(PY2, Y1, PX2 * X1));
            f32x2 d0 = __builtin_elementwise_fma(N2, dt0, SQI2 + S0);
            f32x2 d1 = __builtin_elementwise_fma(N2, dt1, SQI2 + S1);
            d0 = __builtin_elementwise_max(d0, Z02);
            d1 = __builtin_elementwise_max(d1, Z02);
            pk[2 * t]     = pack_keys(d0.x, d0.y);
            pk[2 * t + 1] = pack_keys(d1.x, d1.y);
            pmin = pk_min_u16(pmin, pk[2 * t]);
            pmin = pk_min_u16(pmin, pk[2 * t + 1]);
        }
        unsigned mn = min(pmin & 0xFFFFu, pmin >> 16);   // per-lane min (u16)

        // ---- PER-POINT bitonic sort of 64 lane-minima -> sampled threshold
        #pragma unroll
        for (int k = 2; k <= 64; k <<= 1) {
            #pragma unroll
            for (int jj = k >> 1; jj >= 1; jj >>= 1) {
                const unsigned o = (unsigned)__shfl_xor((int)mn, jj, 64);
                const bool wantmin = (((lane & k) == 0) == ((lane & jj) == 0));
                const bool less = (mn < o);
                if (less != wantmin) mn = o;
            }
        }
        unsigned H = (unsigned)__builtin_amdgcn_readlane((int)mn, 32);

        // wave-uniform count of u16 keys strictly below T (ballot -> scalar)
        auto cnt_lt = [&](unsigned T) -> unsigned {
            unsigned c = 0;
            #pragma unroll
            for (int k2 = 0; k2 < 32; ++k2) {
                c += (unsigned)__popcll(__ballot((pk[k2] & 0xFFFFu) < T));
                c += (unsigned)__popcll(__ballot((pk[k2] >> 16)     < T));
            }
            return c;
        };

        // ---- threshold search in u16 key space ----
        unsigned L = 0u;
        unsigned c = cnt_lt(H);
        if (c < KNN) {                       // raise by octaves (exp LSB = 0x80)
            unsigned step = 0x80u;
            do {
                unsigned Hn = H + step;
                if (Hn > 0xFFFFu) Hn = 0xFFFFu;
                L = H; H = Hn; step <<= 1;
                c = cnt_lt(H);
            } while (c < KNN);
        }
        while (c > 64u && (H - L) > 1u) {
            const unsigned M  = L + ((H - L) >> 1);
            const unsigned cm = cnt_lt(M);
            if (cm >= KNN) { H = M; c = cm; } else { L = M; }
        }

        // ---- compaction: survivor indices only (ballot + mbcnt), ONE site --
        WFENCE();                            // prior scratch consumers done
        unsigned base = 0;
        #pragma unroll
        for (int s = 0; s < 64; ++s) {
            const unsigned kk = (s & 1) ? (pk[s >> 1] >> 16)
                                        : (pk[s >> 1] & 0xFFFFu);
            const bool pred = kk < H;
            const unsigned long long bm = __ballot(pred);
            if (bm) {
                if (pred) {
                    const unsigned pos = base + lane_prefix(bm);
                    if (pos < 64u)
                        poolw[pos] =
                            (unsigned)(((s >> 2) << 8) + (lane << 2) + (s & 3));
                }
                base += (unsigned)__popcll(bm);
            }
        }
        WFENCE();
        const unsigned m = base < 64u ? base : 64u;   // m >= 32 guaranteed

        // ---- exact fp32 keys for pool members (identical op chain) ----
        unsigned myk = 0xFFFFFFFFu;
        unsigned myj = 0u;                   // sentinel, never selected (m>=32)
        if ((unsigned)lane < m) {
            myj = poolw[lane];
            const float qx = s_x[myj], qy = s_y[myj], qz = s_z[myj];
            const float sqj = fmaf(qz, qz, fmaf(qy, qy, qx * qx));
            const float dt  = fmaf(pz, qz, fmaf(py, qy, px * qx));
            float d = fmaf(-2.0f, dt, sqi + sqj);
            d = fmaxf(d, 0.0f);
            myk = __builtin_bit_cast(unsigned, d);
        }

        // ---- partial bitonic: 32-sorts + one merge -> bottom-32 unordered ----
        #pragma unroll
        for (int k = 2; k <= 32; k <<= 1) {
            #pragma unroll
            for (int jj = k >> 1; jj >= 1; jj >>= 1) {
                const unsigned ok = (unsigned)__shfl_xor((int)myk, jj, 64);
                const unsigned oj = (unsigned)__shfl_xor((int)myj, jj, 64);
                const bool wantmin = (((lane & k) == 0) == ((lane & jj) == 0));
                const bool less = (myk < ok) || (myk == ok && myj < oj);
                if (less != wantmin) { myk = ok; myj = oj; }
            }
        }
        {   // k=64, jj=32: lanes 0..31 <- the 32 smallest (unordered)
            const unsigned ok = (unsigned)__shfl_xor((int)myk, 32, 64);
            const unsigned oj = (unsigned)__shfl_xor((int)myj, 32, 64);
            const bool wantmin = ((lane & 32) == 0);
            const bool less = (myk < ok) || (myk == ok && myj < oj);
            if (less != wantmin) { myk = ok; myj = oj; }
        }

        // ---- epilogue: lane = channel e; packed-pair max over 32 selected --
        // Stage deltas in per-wave scratch (pool region dead now); all lanes
        // broadcast-read f32x2 pairs (same-address ds_read = conflict-free)
        // and project with v_pk_fma_f32. Same fma chain per element; fmax
        // regrouping exact on finite floats -> bit-identical output.
        WFENCE();                            // pool reads done before overwrite
        if (lane < KNN) {
            wbuf[lane]      = s_x[myj] - px;
            wbuf[32 + lane] = s_y[myj] - py;
            wbuf[64 + lane] = s_z[myj] - pz;
        }
        WFENCE();                            // deltas visible to whole wave

        const float basev = tbv + pbv + fmaf(pw2, pz, fmaf(pw1, py, pw0 * px));
        f32x2 mx2 = {-3.0e38f, -3.0e38f};
        #pragma unroll
        for (int t = 0; t < 16; ++t) {
            const f32x2 ndx = *(const f32x2*)&wbuf[2 * t];
            const f32x2 ndy = *(const f32x2*)&wbuf[32 + 2 * t];
            const f32x2 ndz = *(const f32x2*)&wbuf[64 + 2 * t];
            const f32x2 proj = __builtin_elementwise_fma(TW2, ndz,
                               __builtin_elementwise_fma(TW1, ndy, TW0 * ndx));
            mx2 = __builtin_elementwise_max(mx2, proj);
        }
        const float mx = fmaxf(mx2.x, mx2.y);
        out[(((size_t)b * NPTS + (size_t)i) << 6) + lane] = mx + basev;
    }
}

extern "C" void kernel_launch(void* const* d_in, const int* in_sizes, int n_in,
                              void* d_out, int out_size, void* d_ws, size_t ws_size,
                              hipStream_t stream) {
    const float* x  = (const float*)d_in[0];
    const float* tw = (const float*)d_in[1];
    const float* tb = (const float*)d_in[2];
    const float* pw = (const float*)d_in[3];
    const float* pb = (const float*)d_in[4];
    float* out = (float*)d_out;

    dim3 grid(8 * 256);   // 2048 blocks x 16 pts, fresh per-point H
    dim3 block(512);
    hipLaunchKernelGGL(edgeconv_knn_kernel, grid, block, 0, stream,
                       x, tw, tb, pw, pb, out);
}